// Round 7
// baseline (434.763 us; speedup 1.0000x reference)
//
#include <hip/hip_runtime.h>

#define DIM 256
#define PDIM 260          // f32 LDS row stride
#define PD2  264          // bf16 LDS row stride
#define NNB 24
#define NEL 8192
#define ROWS 16
#define NT 512
#define CUTOFF 5.0f
#define E1_OFF 524288     // u16 offset of elec1 in ws (byte 1 MB; wprep uses 540 KB)
#define SWP 264           // sWb row stride (u16)

typedef unsigned int u32;
typedef unsigned short u16;
typedef __attribute__((ext_vector_type(8))) short bf16x8;
typedef __attribute__((ext_vector_type(4))) float f32x4;

__device__ __forceinline__ u16 f2b(float f){
  union{float f;u32 i;}v; v.f=f;
  u32 r = v.i + 0x7fffu + ((v.i>>16)&1u);   // RNE
  return (u16)(r>>16);
}
__device__ __forceinline__ float b2f(u16 u){
  union{u32 i;float f;}v; v.i = ((u32)u)<<16; return v.f;
}
__device__ __forceinline__ float fast_silu(float x){
  float e = __builtin_amdgcn_exp2f(-1.44269504088896340f * x);
  return x * __builtin_amdgcn_rcpf(1.0f + e);
}

// Pre-pass. Blocks 0..1023: Wt[mat][n][k] = bf16(W[k][n]) (4 x 256x256).
// Block 1024: Wcat (legacy, unused by k2 now but cheap).
__global__ __launch_bounds__(256)
void wprep(const float* __restrict__ W0, const float* __restrict__ W1,
           const float* __restrict__ W2, const float* __restrict__ W3,
           const float* __restrict__ Wsame, const float* __restrict__ Wdiff,
           u16* __restrict__ ws){
  if (blockIdx.x < 1024){
    const int mat = blockIdx.x >> 8;
    const int n   = blockIdx.x & 255;
    const int k   = threadIdx.x;
    const float* W = (mat==0)?W0:(mat==1)?W1:(mat==2)?W2:W3;
    ws[(mat<<16) + (n<<8) + k] = f2b(W[(k<<8) + n]);
  } else {
    const int n = threadIdx.x;
    u16* dst = ws + 4*65536 + n*32;
    #pragma unroll
    for (int kk = 0; kk < 16; kk++){
      dst[kk]    = f2b(Wsame[kk*DIM + n]);
      dst[16+kk] = f2b(Wdiff[kk*DIM + n]);
    }
  }
}

// MFMA GEMM on a 16x256 tile. Wt = bf16 W^T [n][k]. 8 waves, wave = 32 cols.
// MODE 2: silu(. + extraGbl), inner barrier, -> sR1
// MODE 3: (silu(.) + b2f(sE1b)) * scl -> outGbl
template<int MODE, int ABF16>
__device__ __forceinline__ void gemm_mfma(
    const void* A, u16* sE1b, float* sR1,
    const u16* __restrict__ Wt, const float* __restrict__ bias,
    const float* __restrict__ extraGbl, float* __restrict__ outGbl,
    float scl, int n0, int t)
{
  const int lane = t & 63;
  const int ln   = lane & 15;
  const int quad = lane >> 4;
  const int nt0  = (t >> 6) << 1;
  f32x4 acc0 = {0.f,0.f,0.f,0.f};
  f32x4 acc1 = {0.f,0.f,0.f,0.f};
  const u16* bp0 = Wt + (nt0*16 + ln)*DIM;
  const u16* bp1 = bp0 + 16*DIM;
  #pragma unroll
  for (int ks = 0; ks < 8; ks++){
    const int k0 = ks*32 + quad*8;
    bf16x8 af;
    if (ABF16){
      af = *(const bf16x8*)((const u16*)A + ln*PD2 + k0);
    } else {
      const float* arow = (const float*)A + ln*PDIM;
      float4 a01 = *(const float4*)(arow + k0);
      float4 a23 = *(const float4*)(arow + k0 + 4);
      af[0]=(short)f2b(a01.x); af[1]=(short)f2b(a01.y);
      af[2]=(short)f2b(a01.z); af[3]=(short)f2b(a01.w);
      af[4]=(short)f2b(a23.x); af[5]=(short)f2b(a23.y);
      af[6]=(short)f2b(a23.z); af[7]=(short)f2b(a23.w);
    }
    bf16x8 b0 = *(const bf16x8*)(bp0 + k0);
    bf16x8 b1 = *(const bf16x8*)(bp1 + k0);
    acc0 = __builtin_amdgcn_mfma_f32_16x16x32_bf16(af, b0, acc0, 0, 0, 0);
    acc1 = __builtin_amdgcn_mfma_f32_16x16x32_bf16(af, b1, acc1, 0, 0, 0);
  }
  if (MODE == 2) __syncthreads();
  #pragma unroll
  for (int r = 0; r < 4; r++){
    const int m = quad*4 + r;
    #pragma unroll
    for (int tt = 0; tt < 2; tt++){
      const int n = (nt0+tt)*16 + ln;
      float v = (tt ? acc1[r] : acc0[r]) + bias[n];
      if (MODE == 2) v += extraGbl[(size_t)(n0+m)*DIM + n];
      v = fast_silu(v);
      if (MODE == 3) outGbl[(size_t)(n0+m)*DIM + n] = (v + b2f(sE1b[m*PD2 + n])) * scl;
      else           sR1[m*PDIM + n] = v;
    }
  }
}

// ---- K1: elec1 = silu(elec @ W_in + b_in), bf16 -> ws. ----
__global__ __launch_bounds__(NT, 8)
void k1_gemm1(const float* __restrict__ elec, const float* __restrict__ bin,
              const u16* __restrict__ Wt, u16* __restrict__ elec1g)
{
  const int t  = threadIdx.x;
  const int n0 = blockIdx.x * ROWS;
  const int lane = t & 63;
  const int ln   = lane & 15;
  const int quad = lane >> 4;
  const int nt0  = (t >> 6) << 1;
  f32x4 acc0 = {0.f,0.f,0.f,0.f};
  f32x4 acc1 = {0.f,0.f,0.f,0.f};
  const u16* bp0 = Wt + (nt0*16 + ln)*DIM;
  const u16* bp1 = bp0 + 16*DIM;
  const float* arow = elec + (size_t)(n0 + ln)*DIM;
  #pragma unroll
  for (int ks = 0; ks < 8; ks++){
    const int k0 = ks*32 + quad*8;
    float4 a01 = *(const float4*)(arow + k0);
    float4 a23 = *(const float4*)(arow + k0 + 4);
    bf16x8 af;
    af[0]=(short)f2b(a01.x); af[1]=(short)f2b(a01.y);
    af[2]=(short)f2b(a01.z); af[3]=(short)f2b(a01.w);
    af[4]=(short)f2b(a23.x); af[5]=(short)f2b(a23.y);
    af[6]=(short)f2b(a23.z); af[7]=(short)f2b(a23.w);
    bf16x8 b0 = *(const bf16x8*)(bp0 + k0);
    bf16x8 b1 = *(const bf16x8*)(bp1 + k0);
    acc0 = __builtin_amdgcn_mfma_f32_16x16x32_bf16(af, b0, acc0, 0, 0, 0);
    acc1 = __builtin_amdgcn_mfma_f32_16x16x32_bf16(af, b1, acc1, 0, 0, 0);
  }
  #pragma unroll
  for (int r = 0; r < 4; r++){
    const int m = quad*4 + r;
    #pragma unroll
    for (int tt = 0; tt < 2; tt++){
      const int n = (nt0+tt)*16 + ln;
      float v = fast_silu((tt ? acc1[r] : acc0[r]) + bin[n]);
      elec1g[(size_t)(n0+m)*DIM + n] = f2b(v);
    }
  }
}

// ---- K2: one block per electron row. 4 waves; wave w streams hinit rows
//      k=6w..6w+5 (6 KB contiguous) as 6 independent float4 loads issued at
//      kernel entry; gamma on VALU from LDS-staged Wsame/Wdiff (bf16). ----
__global__ __launch_bounds__(256, 4)
void k2_msg(const float* __restrict__ rpos, const float* __restrict__ rnb,
            const int* __restrict__ s, const int* __restrict__ snb,
            const float* __restrict__ hinit,
            const float* __restrict__ eesc, const float* __restrict__ eek,
            const float* __restrict__ eeb,  const float* __restrict__ Wf,
            const float* __restrict__ bfb,
            const float* __restrict__ Wsame, const float* __restrict__ Wdiff,
            const u16* __restrict__ elec1g, float* __restrict__ hmsg)
{
  __shared__ u16   sWb[32*SWP];    // bf16 W rows: 0-15 same, 16-31 diff (16.5 KB)
  __shared__ float sPar[824];      // Wf|eek|eeb|bfb|eesc (3.3 KB)
  __shared__ float sBeta[NNB*16];  // f32 beta (1.5 KB)
  __shared__ float sRed[4][260];   // cross-wave partials (4.1 KB)
  __shared__ u32   sMask0;
  const int t    = threadIdx.x;
  const int n    = blockIdx.x;
  const int w    = t >> 6;
  const int lane = t & 63;
  const int c0   = lane << 2;      // this lane's 4 columns

  // ---- issue the row's global streams immediately (latency hides under
  //      staging + filter); sched_barrier pins them at the top ----
  ushort4 e1u = *(const ushort4*)(elec1g + (size_t)n*DIM + c0);
  const float* hp = hinit + ((size_t)n*NNB + w*6)*DIM + c0;
  float4 h0 = *(const float4*)(hp + 0*DIM);
  float4 h1 = *(const float4*)(hp + 1*DIM);
  float4 h2 = *(const float4*)(hp + 2*DIM);
  float4 h3 = *(const float4*)(hp + 3*DIM);
  float4 h4 = *(const float4*)(hp + 4*DIM);
  float4 h5 = *(const float4*)(hp + 5*DIM);
  __builtin_amdgcn_sched_barrier(0);

  // ---- stage W (bf16) + params ----
  if (t == 0) sMask0 = 0u;
  #pragma unroll
  for (int it = 0; it < 8; it++){
    const int i = t + it*256;              // 0..2047
    const int r  = i >> 6;
    const int c4 = (i & 63) << 2;
    const float* Wsrc = (r < 16) ? (Wsame + r*DIM + c4) : (Wdiff + (r-16)*DIM + c4);
    float4 v = *(const float4*)Wsrc;
    ushort4 b;
    b.x=f2b(v.x); b.y=f2b(v.y); b.z=f2b(v.z); b.w=f2b(v.w);
    *(ushort4*)&sWb[r*SWP + c4] = b;
  }
  for (int i = t; i < 824; i += 256){
    float v;
    if (i < 640)      v = Wf[i];
    else if (i < 768) v = eek[i-640];
    else if (i < 800) v = eeb[i-768];
    else if (i < 816) v = bfb[i-800];
    else              v = eesc[i-816];
    sPar[i] = v;
  }
  __syncthreads();

  // ---- pairwise filter: 96 threads, 4 threads per neighbor (j4 split) ----
  if (t < 4*NNB) {
    const int pr = t >> 2;
    const int j4 = t & 3;
    const float* rp  = rpos + n*3;
    const float* rnp = rnb + (n*NNB + pr)*3;
    float dx = rnp[0] - rp[0];
    float dy = rnp[1] - rp[1];
    float dz = rnp[2] - rp[2];
    float dist = sqrtf(dx*dx + dy*dy + dz*dz + 1e-12f);
    float feats[4] = {dist, dx, dy, dz};
    float h[32];
    #pragma unroll
    for (int f4 = 0; f4 < 8; f4++){
      float4 a4 = *(const float4*)&sPar[768 + 4*f4];
      float av[4] = {a4.x, a4.y, a4.z, a4.w};
      #pragma unroll
      for (int i = 0; i < 4; i++){
        float4 kv = *(const float4*)&sPar[640 + i*32 + 4*f4];
        av[0]+=feats[i]*kv.x; av[1]+=feats[i]*kv.y; av[2]+=feats[i]*kv.z; av[3]+=feats[i]*kv.w;
      }
      h[4*f4+0]=fast_silu(av[0]); h[4*f4+1]=fast_silu(av[1]);
      h[4*f4+2]=fast_silu(av[2]); h[4*f4+3]=fast_silu(av[3]);
    }
    float env[8];
    #pragma unroll
    for (int e = 0; e < 8; e++){
      float q = dist * __builtin_amdgcn_rcpf(sPar[816 + e]);
      env[e] = __builtin_amdgcn_exp2f(-1.44269504088896340f * q * q);
    }
    float xx = dist * (1.0f/CUTOFF);
    float cut = (dist < CUTOFF) ? (1.0f-xx)*(1.0f-xx)*(1.0f+2.0f*xx) : 0.0f;
    float4 a4 = *(const float4*)&sPar[800 + 4*j4];
    float av[4] = {a4.x, a4.y, a4.z, a4.w};
    #pragma unroll
    for (int f = 0; f < 40; f++){
      float val = (f < 32) ? h[f] : env[f-32];
      float4 wv = *(const float4*)&sPar[f*16 + 4*j4];
      av[0]+=val*wv.x; av[1]+=val*wv.y; av[2]+=val*wv.z; av[3]+=val*wv.w;
    }
    *(float4*)&sBeta[pr*16 + j4*4] =
        make_float4(av[0]*cut, av[1]*cut, av[2]*cut, av[3]*cut);
    if (j4 == 0 && s[n] == snb[n*NNB + pr]) atomicOr(&sMask0, 1u << pr);
  }
  __syncthreads();

  // ---- gamma for this wave's 6 ks on VALU (j-outer, both rows + cndmask) ----
  const u32 mb = sMask0;
  float g[6][4];
  #pragma unroll
  for (int i = 0; i < 6; i++){ g[i][0]=0.f; g[i][1]=0.f; g[i][2]=0.f; g[i][3]=0.f; }
  for (int j = 0; j < 16; j++){
    ushort4 su = *(const ushort4*)&sWb[j*SWP + c0];
    ushort4 du = *(const ushort4*)&sWb[(j+16)*SWP + c0];
    float ws0=b2f(su.x), ws1=b2f(su.y), ws2=b2f(su.z), ws3=b2f(su.w);
    float wd0=b2f(du.x), wd1=b2f(du.y), wd2=b2f(du.z), wd3=b2f(du.w);
    #pragma unroll
    for (int i = 0; i < 6; i++){
      const int k = w*6 + i;
      const float b = sBeta[k*16 + j];
      const bool m = ((mb >> k) & 1u) != 0u;
      g[i][0] += b * (m ? ws0 : wd0);
      g[i][1] += b * (m ? ws1 : wd1);
      g[i][2] += b * (m ? ws2 : wd2);
      g[i][3] += b * (m ? ws3 : wd3);
    }
  }

  // ---- consume hinit stream: partial hm over this wave's 6 ks ----
  float e0=b2f(e1u.x), e1=b2f(e1u.y), e2=b2f(e1u.z), e3=b2f(e1u.w);
  float hm0=0.f, hm1=0.f, hm2=0.f, hm3=0.f;
#define CONSUME(i, hv) \
  hm0 += fast_silu(e0 + hv.x) * g[i][0]; \
  hm1 += fast_silu(e1 + hv.y) * g[i][1]; \
  hm2 += fast_silu(e2 + hv.z) * g[i][2]; \
  hm3 += fast_silu(e3 + hv.w) * g[i][3];
  CONSUME(0, h0) CONSUME(1, h1) CONSUME(2, h2)
  CONSUME(3, h3) CONSUME(4, h4) CONSUME(5, h5)
#undef CONSUME

  // ---- cross-wave reduction (4 partials per column) ----
  *(float4*)&sRed[w][c0] = make_float4(hm0, hm1, hm2, hm3);
  __syncthreads();
  {
    float r = sRed[0][t] + sRed[1][t] + sRed[2][t] + sRed[3][t];
    hmsg[(size_t)n*DIM + t] = r;
  }
}

// ---- K3: GEMM2 (+hmsg) -> GEMM3 (+msg) -> GEMM4 (+elec1 residual) -> out ----
__global__ __launch_bounds__(NT, 8)
void k3_gemms(const float* __restrict__ msg, const u16* __restrict__ elec1g,
              const float* __restrict__ b1, const float* __restrict__ b2,
              const float* __restrict__ b3, const float* __restrict__ scalep,
              const u16* __restrict__ Wt, float* __restrict__ out)
{
  __shared__ float sR1[ROWS*PDIM];        // t1 -> t2              (16.6 KB)
  __shared__ u16   sE1b[ROWS*PD2];        // elec1 bf16            (8.45 KB)
  const int t  = threadIdx.x;
  const int n0 = blockIdx.x * ROWS;

  // stage elec1 (bf16) into PD2-padded LDS
  {
    const u32* e1u = (const u32*)elec1g;
    #pragma unroll
    for (int h = 0; h < 8; h++){
      const int i   = t + h*NT;            // 0..4095, 128 u32 per row
      const int row = i >> 7;
      const int c2  = i & 127;
      *(u32*)&sE1b[row*PD2 + 2*c2] = e1u[(size_t)(n0+row)*128 + c2];
    }
  }
  __syncthreads();

  const float scl = scalep[0];
  // GEMM2: t1 = silu(elec1 @ W1 + b1 + hmsg[global=out]) -> sR1
  gemm_mfma<2,1>(sE1b, sE1b, sR1, Wt + (1<<16), b1, out, nullptr, 0.f, n0, t);
  __syncthreads();
  // GEMM3: t2 = silu(t1 @ W2 + b2 + msg) -> sR1
  gemm_mfma<2,0>(sR1, sE1b, sR1, Wt + (2<<16), b2, msg, nullptr, 0.f, n0, t);
  __syncthreads();
  // GEMM4: out = (silu(t2 @ W3 + b3) + elec1) * scl
  gemm_mfma<3,0>(sR1, sE1b, sR1, Wt + (3<<16), b3, nullptr, out, scl, n0, t);
}

extern "C" void kernel_launch(void* const* d_in, const int* in_sizes, int n_in,
                              void* d_out, int out_size, void* d_ws, size_t ws_size,
                              hipStream_t stream) {
  (void)in_sizes; (void)n_in; (void)ws_size; (void)out_size;
  const float* elec  = (const float*)d_in[0];
  const float* msg   = (const float*)d_in[1];
  const float* rpos  = (const float*)d_in[2];
  const float* rnb   = (const float*)d_in[3];
  const int*   s     = (const int*)d_in[4];
  const int*   snb   = (const int*)d_in[5];
  const float* hinit = (const float*)d_in[6];
  const float* Win   = (const float*)d_in[7];
  const float* bin   = (const float*)d_in[8];
  const float* eesc  = (const float*)d_in[9];
  const float* eek   = (const float*)d_in[10];
  const float* eeb   = (const float*)d_in[11];
  const float* Wf    = (const float*)d_in[12];
  const float* bfb   = (const float*)d_in[13];
  const float* Wsame = (const float*)d_in[14];
  const float* Wdiff = (const float*)d_in[15];
  const float* W1    = (const float*)d_in[16];
  const float* b1    = (const float*)d_in[17];
  const float* W2    = (const float*)d_in[18];
  const float* b2    = (const float*)d_in[19];
  const float* W3    = (const float*)d_in[20];
  const float* b3    = (const float*)d_in[21];
  const float* scl   = (const float*)d_in[22];
  float* outp        = (float*)d_out;
  u16*   wt          = (u16*)d_ws;        // weights 0.54 MB + elec1 4 MB at E1_OFF
  u16*   elec1g      = wt + E1_OFF;

  wprep<<<dim3(1025), dim3(256), 0, stream>>>(Win, W1, W2, W3, Wsame, Wdiff, wt);
  k1_gemm1<<<dim3(NEL/ROWS), dim3(NT), 0, stream>>>(elec, bin, wt, elec1g);
  k2_msg<<<dim3(NEL), dim3(256), 0, stream>>>(
      rpos, rnb, s, snb, hinit, eesc, eek, eeb, Wf, bfb,
      Wsame, Wdiff, elec1g, outp);
  k3_gemms<<<dim3(NEL/ROWS), dim3(NT), 0, stream>>>(
      msg, elec1g, b1, b2, b3, scl, wt, outp);
}

// Round 8
// 416.518 us; speedup vs baseline: 1.0438x; 1.0438x over previous
//
#include <hip/hip_runtime.h>

#define DIM 256
#define PDIM 260          // f32 LDS row stride
#define PD2  264          // bf16 LDS row stride
#define NNB 24
#define NEL 8192
#define ROWS 16
#define NT 512
#define CUTOFF 5.0f
#define E1_OFF 524288     // u16 offset of elec1 in ws (byte 1 MB; wprep uses 540 KB)
#define SGP 260           // sG row stride (f32)

typedef unsigned int u32;
typedef unsigned short u16;
typedef __attribute__((ext_vector_type(8))) short bf16x8;
typedef __attribute__((ext_vector_type(4))) float f32x4;

__device__ __forceinline__ u16 f2b(float f){
  union{float f;u32 i;}v; v.f=f;
  u32 r = v.i + 0x7fffu + ((v.i>>16)&1u);   // RNE
  return (u16)(r>>16);
}
__device__ __forceinline__ float b2f(u16 u){
  union{u32 i;float f;}v; v.i = ((u32)u)<<16; return v.f;
}
__device__ __forceinline__ float fast_silu(float x){
  float e = __builtin_amdgcn_exp2f(-1.44269504088896340f * x);
  return x * __builtin_amdgcn_rcpf(1.0f + e);
}

// Pre-pass. Blocks 0..1023: Wt[mat][n][k] = bf16(W[k][n]) (4 x 256x256).
// Block 1024: Wcat[c][kk] = bf16(kk<16 ? Wsame[kk][c] : Wdiff[kk-16][c])  (256x32).
__global__ __launch_bounds__(256)
void wprep(const float* __restrict__ W0, const float* __restrict__ W1,
           const float* __restrict__ W2, const float* __restrict__ W3,
           const float* __restrict__ Wsame, const float* __restrict__ Wdiff,
           u16* __restrict__ ws){
  if (blockIdx.x < 1024){
    const int mat = blockIdx.x >> 8;
    const int n   = blockIdx.x & 255;
    const int k   = threadIdx.x;
    const float* W = (mat==0)?W0:(mat==1)?W1:(mat==2)?W2:W3;
    ws[(mat<<16) + (n<<8) + k] = f2b(W[(k<<8) + n]);
  } else {
    const int n = threadIdx.x;
    u16* dst = ws + 4*65536 + n*32;
    #pragma unroll
    for (int kk = 0; kk < 16; kk++){
      dst[kk]    = f2b(Wsame[kk*DIM + n]);
      dst[16+kk] = f2b(Wdiff[kk*DIM + n]);
    }
  }
}

// MFMA GEMM on a 16x256 tile. Wt = bf16 W^T [n][k]. 8 waves, wave = 32 cols.
// MODE 2: silu(. + extraGbl), inner barrier, -> sR1
// MODE 3: (silu(.) + b2f(sE1b)) * scl -> outGbl
template<int MODE, int ABF16>
__device__ __forceinline__ void gemm_mfma(
    const void* A, u16* sE1b, float* sR1,
    const u16* __restrict__ Wt, const float* __restrict__ bias,
    const float* __restrict__ extraGbl, float* __restrict__ outGbl,
    float scl, int n0, int t)
{
  const int lane = t & 63;
  const int ln   = lane & 15;
  const int quad = lane >> 4;
  const int nt0  = (t >> 6) << 1;
  f32x4 acc0 = {0.f,0.f,0.f,0.f};
  f32x4 acc1 = {0.f,0.f,0.f,0.f};
  const u16* bp0 = Wt + (nt0*16 + ln)*DIM;
  const u16* bp1 = bp0 + 16*DIM;
  #pragma unroll
  for (int ks = 0; ks < 8; ks++){
    const int k0 = ks*32 + quad*8;
    bf16x8 af;
    if (ABF16){
      af = *(const bf16x8*)((const u16*)A + ln*PD2 + k0);
    } else {
      const float* arow = (const float*)A + ln*PDIM;
      float4 a01 = *(const float4*)(arow + k0);
      float4 a23 = *(const float4*)(arow + k0 + 4);
      af[0]=(short)f2b(a01.x); af[1]=(short)f2b(a01.y);
      af[2]=(short)f2b(a01.z); af[3]=(short)f2b(a01.w);
      af[4]=(short)f2b(a23.x); af[5]=(short)f2b(a23.y);
      af[6]=(short)f2b(a23.z); af[7]=(short)f2b(a23.w);
    }
    bf16x8 b0 = *(const bf16x8*)(bp0 + k0);
    bf16x8 b1 = *(const bf16x8*)(bp1 + k0);
    acc0 = __builtin_amdgcn_mfma_f32_16x16x32_bf16(af, b0, acc0, 0, 0, 0);
    acc1 = __builtin_amdgcn_mfma_f32_16x16x32_bf16(af, b1, acc1, 0, 0, 0);
  }
  if (MODE == 2) __syncthreads();
  #pragma unroll
  for (int r = 0; r < 4; r++){
    const int m = quad*4 + r;
    #pragma unroll
    for (int tt = 0; tt < 2; tt++){
      const int n = (nt0+tt)*16 + ln;
      float v = (tt ? acc1[r] : acc0[r]) + bias[n];
      if (MODE == 2) v += extraGbl[(size_t)(n0+m)*DIM + n];
      v = fast_silu(v);
      if (MODE == 3) outGbl[(size_t)(n0+m)*DIM + n] = (v + b2f(sE1b[m*PD2 + n])) * scl;
      else           sR1[m*PDIM + n] = v;
    }
  }
}

// ---- K1: elec1 = silu(elec @ W_in + b_in), bf16 -> ws. ----
__global__ __launch_bounds__(NT, 8)
void k1_gemm1(const float* __restrict__ elec, const float* __restrict__ bin,
              const u16* __restrict__ Wt, u16* __restrict__ elec1g)
{
  const int t  = threadIdx.x;
  const int n0 = blockIdx.x * ROWS;
  const int lane = t & 63;
  const int ln   = lane & 15;
  const int quad = lane >> 4;
  const int nt0  = (t >> 6) << 1;
  f32x4 acc0 = {0.f,0.f,0.f,0.f};
  f32x4 acc1 = {0.f,0.f,0.f,0.f};
  const u16* bp0 = Wt + (nt0*16 + ln)*DIM;
  const u16* bp1 = bp0 + 16*DIM;
  const float* arow = elec + (size_t)(n0 + ln)*DIM;
  #pragma unroll
  for (int ks = 0; ks < 8; ks++){
    const int k0 = ks*32 + quad*8;
    float4 a01 = *(const float4*)(arow + k0);
    float4 a23 = *(const float4*)(arow + k0 + 4);
    bf16x8 af;
    af[0]=(short)f2b(a01.x); af[1]=(short)f2b(a01.y);
    af[2]=(short)f2b(a01.z); af[3]=(short)f2b(a01.w);
    af[4]=(short)f2b(a23.x); af[5]=(short)f2b(a23.y);
    af[6]=(short)f2b(a23.z); af[7]=(short)f2b(a23.w);
    bf16x8 b0 = *(const bf16x8*)(bp0 + k0);
    bf16x8 b1 = *(const bf16x8*)(bp1 + k0);
    acc0 = __builtin_amdgcn_mfma_f32_16x16x32_bf16(af, b0, acc0, 0, 0, 0);
    acc1 = __builtin_amdgcn_mfma_f32_16x16x32_bf16(af, b1, acc1, 0, 0, 0);
  }
  #pragma unroll
  for (int r = 0; r < 4; r++){
    const int m = quad*4 + r;
    #pragma unroll
    for (int tt = 0; tt < 2; tt++){
      const int n = (nt0+tt)*16 + ln;
      float v = fast_silu((tt ? acc1[r] : acc0[r]) + bin[n]);
      elec1g[(size_t)(n0+m)*DIM + n] = f2b(v);
    }
  }
}

// ---- K2: one block per electron row; gamma via masked MFMA (A=Wcat, B=beta),
//      LDS gamma tile, contiguous hinit streams pinned at block start. ----
__global__ __launch_bounds__(256, 4)
void k2_msg(const float* __restrict__ rpos, const float* __restrict__ rnb,
            const int* __restrict__ s, const int* __restrict__ snb,
            const float* __restrict__ hinit,
            const float* __restrict__ eesc, const float* __restrict__ eek,
            const float* __restrict__ eeb,  const float* __restrict__ Wf,
            const float* __restrict__ bfb,
            const u16* __restrict__ Wt,
            const u16* __restrict__ elec1g, float* __restrict__ hmsg)
{
  __shared__ float sG[NNB*SGP];    // gamma [24][260] f32          (24.96 KB)
  __shared__ float sPar[824];      // Wf|eek|eeb|bfb|eesc          (3.3 KB)
  __shared__ u16   sBetaB[32*16];  // bf16 beta rows 0-23; 24-31=0 (1 KB)
  __shared__ float sRed[4][260];   // cross-wave partials          (4.2 KB)
  __shared__ u32   sMask0;
  const int t    = threadIdx.x;
  const int n    = blockIdx.x;
  const int w    = t >> 6;
  const int lane = t & 63;
  const int ln   = lane & 15;
  const int quad = lane >> 4;
  const int C0   = w << 6;         // wave's 64-col gamma slice
  const int c0   = lane << 2;      // lane's 4 columns (consume)

  const u16* Wcat = Wt + 4*65536;

  // ---- issue ALL global streams up front; sched_barrier pins them ----
  ushort4 e1u = *(const ushort4*)(elec1g + (size_t)n*DIM + c0);
  const float* hp = hinit + ((size_t)n*NNB + w*6)*DIM + c0;
  float4 h0 = *(const float4*)(hp + 0*DIM);
  float4 h1 = *(const float4*)(hp + 1*DIM);
  float4 h2 = *(const float4*)(hp + 2*DIM);
  float4 h3 = *(const float4*)(hp + 3*DIM);
  float4 h4 = *(const float4*)(hp + 4*DIM);
  float4 h5 = *(const float4*)(hp + 5*DIM);
  // MFMA A-operands: lane ln -> gamma col C0+ct*16+ln, j' chunk quad*8 (L2-hot)
  bf16x8 wv0 = *(const bf16x8*)(Wcat + (C0 + 0*16 + ln)*32 + quad*8);
  bf16x8 wv1 = *(const bf16x8*)(Wcat + (C0 + 1*16 + ln)*32 + quad*8);
  bf16x8 wv2 = *(const bf16x8*)(Wcat + (C0 + 2*16 + ln)*32 + quad*8);
  bf16x8 wv3 = *(const bf16x8*)(Wcat + (C0 + 3*16 + ln)*32 + quad*8);
  __builtin_amdgcn_sched_barrier(0);

  // ---- stage params; zero beta pad rows; zero mask ----
  if (t == 0) sMask0 = 0u;
  if (t < 128) sBetaB[24*16 + t] = 0;      // rows 24..31
  for (int i = t; i < 824; i += 256){
    float v;
    if (i < 640)      v = Wf[i];
    else if (i < 768) v = eek[i-640];
    else if (i < 800) v = eeb[i-768];
    else if (i < 816) v = bfb[i-800];
    else              v = eesc[i-816];
    sPar[i] = v;
  }
  __syncthreads();

  // ---- pairwise filter: 96 threads, 4 per neighbor (j4 split) -> bf16 beta ----
  if (t < 4*NNB) {
    const int pr = t >> 2;
    const int j4 = t & 3;
    const float* rp  = rpos + n*3;
    const float* rnp = rnb + (n*NNB + pr)*3;
    float dx = rnp[0] - rp[0];
    float dy = rnp[1] - rp[1];
    float dz = rnp[2] - rp[2];
    float dist = sqrtf(dx*dx + dy*dy + dz*dz + 1e-12f);
    float feats[4] = {dist, dx, dy, dz};
    float h[32];
    #pragma unroll
    for (int f4 = 0; f4 < 8; f4++){
      float4 a4 = *(const float4*)&sPar[768 + 4*f4];
      float av[4] = {a4.x, a4.y, a4.z, a4.w};
      #pragma unroll
      for (int i = 0; i < 4; i++){
        float4 kv = *(const float4*)&sPar[640 + i*32 + 4*f4];
        av[0]+=feats[i]*kv.x; av[1]+=feats[i]*kv.y; av[2]+=feats[i]*kv.z; av[3]+=feats[i]*kv.w;
      }
      h[4*f4+0]=fast_silu(av[0]); h[4*f4+1]=fast_silu(av[1]);
      h[4*f4+2]=fast_silu(av[2]); h[4*f4+3]=fast_silu(av[3]);
    }
    float env[8];
    #pragma unroll
    for (int e = 0; e < 8; e++){
      float q = dist * __builtin_amdgcn_rcpf(sPar[816 + e]);
      env[e] = __builtin_amdgcn_exp2f(-1.44269504088896340f * q * q);
    }
    float xx = dist * (1.0f/CUTOFF);
    float cut = (dist < CUTOFF) ? (1.0f-xx)*(1.0f-xx)*(1.0f+2.0f*xx) : 0.0f;
    float4 a4 = *(const float4*)&sPar[800 + 4*j4];
    float av[4] = {a4.x, a4.y, a4.z, a4.w};
    #pragma unroll
    for (int f = 0; f < 40; f++){
      float val = (f < 32) ? h[f] : env[f-32];
      float4 wv = *(const float4*)&sPar[f*16 + 4*j4];
      av[0]+=val*wv.x; av[1]+=val*wv.y; av[2]+=val*wv.z; av[3]+=val*wv.w;
    }
    ushort4 bv;
    bv.x = f2b(av[0]*cut); bv.y = f2b(av[1]*cut);
    bv.z = f2b(av[2]*cut); bv.w = f2b(av[3]*cut);
    *(ushort4*)&sBetaB[pr*16 + j4*4] = bv;
    if (j4 == 0 && s[n] == snb[n*NNB + pr]) atomicOr(&sMask0, 1u << pr);
  }
  __syncthreads();   // beta + mask ready

  // ---- gamma via MFMA: D[c=C0+ct*16+quad*4+r][k=kt*16+ln] -> sG[k][c] ----
  {
    const u32 mb = sMask0;
    // B-operand frags: beta row (k) & mask; kt=0 -> k=ln, kt=1 -> k=16+ln
    bf16x8 r0v = *(const bf16x8*)&sBetaB[ln*16 + (quad&1)*8];
    bf16x8 r1v = *(const bf16x8*)&sBetaB[(16+ln)*16 + (quad&1)*8];
    const u16 km0 = (u16)((((u32)(quad>>1) ^ ((mb>>ln)&1u)) != 0u) ? 0xFFFFu : 0u);
    const u16 km1 = (u16)((((u32)(quad>>1) ^ ((mb>>(16+ln))&1u)) != 0u) ? 0xFFFFu : 0u);
    bf16x8 bf0, bf1;
    #pragma unroll
    for (int j = 0; j < 8; j++){
      bf0[j] = (short)((u16)r0v[j] & km0);
      bf1[j] = (short)((u16)r1v[j] & km1);
    }
    f32x4 z = {0.f,0.f,0.f,0.f};
    f32x4 d;
    const int colw = quad*4;   // c-offset within 16-tile held by this lane
    d = __builtin_amdgcn_mfma_f32_16x16x32_bf16(wv0, bf0, z, 0, 0, 0);
    *(f32x4*)&sG[ln*SGP + C0 + 0*16 + colw] = d;
    d = __builtin_amdgcn_mfma_f32_16x16x32_bf16(wv0, bf1, z, 0, 0, 0);
    if (ln < 8) *(f32x4*)&sG[(16+ln)*SGP + C0 + 0*16 + colw] = d;
    d = __builtin_amdgcn_mfma_f32_16x16x32_bf16(wv1, bf0, z, 0, 0, 0);
    *(f32x4*)&sG[ln*SGP + C0 + 1*16 + colw] = d;
    d = __builtin_amdgcn_mfma_f32_16x16x32_bf16(wv1, bf1, z, 0, 0, 0);
    if (ln < 8) *(f32x4*)&sG[(16+ln)*SGP + C0 + 1*16 + colw] = d;
    d = __builtin_amdgcn_mfma_f32_16x16x32_bf16(wv2, bf0, z, 0, 0, 0);
    *(f32x4*)&sG[ln*SGP + C0 + 2*16 + colw] = d;
    d = __builtin_amdgcn_mfma_f32_16x16x32_bf16(wv2, bf1, z, 0, 0, 0);
    if (ln < 8) *(f32x4*)&sG[(16+ln)*SGP + C0 + 2*16 + colw] = d;
    d = __builtin_amdgcn_mfma_f32_16x16x32_bf16(wv3, bf0, z, 0, 0, 0);
    *(f32x4*)&sG[ln*SGP + C0 + 3*16 + colw] = d;
    d = __builtin_amdgcn_mfma_f32_16x16x32_bf16(wv3, bf1, z, 0, 0, 0);
    if (ln < 8) *(f32x4*)&sG[(16+ln)*SGP + C0 + 3*16 + colw] = d;
  }
  __syncthreads();   // gamma ready

  // ---- consume hinit stream against gamma; partial over this wave's 6 ks ----
  float e0=b2f(e1u.x), e1=b2f(e1u.y), e2=b2f(e1u.z), e3=b2f(e1u.w);
  float hm0=0.f, hm1=0.f, hm2=0.f, hm3=0.f;
#define CONSUME(i, hv) { \
  float4 g = *(const float4*)&sG[(w*6 + (i))*SGP + c0]; \
  hm0 += fast_silu(e0 + hv.x) * g.x; \
  hm1 += fast_silu(e1 + hv.y) * g.y; \
  hm2 += fast_silu(e2 + hv.z) * g.z; \
  hm3 += fast_silu(e3 + hv.w) * g.w; }
  CONSUME(0, h0) CONSUME(1, h1) CONSUME(2, h2)
  CONSUME(3, h3) CONSUME(4, h4) CONSUME(5, h5)
#undef CONSUME

  // ---- cross-wave reduction (4 partials per column) ----
  *(float4*)&sRed[w][c0] = make_float4(hm0, hm1, hm2, hm3);
  __syncthreads();
  {
    float r = sRed[0][t] + sRed[1][t] + sRed[2][t] + sRed[3][t];
    hmsg[(size_t)n*DIM + t] = r;
  }
}

// ---- K3: GEMM2 (+hmsg) -> GEMM3 (+msg) -> GEMM4 (+elec1 residual) -> out ----
__global__ __launch_bounds__(NT, 8)
void k3_gemms(const float* __restrict__ msg, const u16* __restrict__ elec1g,
              const float* __restrict__ b1, const float* __restrict__ b2,
              const float* __restrict__ b3, const float* __restrict__ scalep,
              const u16* __restrict__ Wt, float* __restrict__ out)
{
  __shared__ float sR1[ROWS*PDIM];        // t1 -> t2              (16.6 KB)
  __shared__ u16   sE1b[ROWS*PD2];        // elec1 bf16            (8.45 KB)
  const int t  = threadIdx.x;
  const int n0 = blockIdx.x * ROWS;

  // stage elec1 (bf16) into PD2-padded LDS
  {
    const u32* e1u = (const u32*)elec1g;
    #pragma unroll
    for (int h = 0; h < 8; h++){
      const int i   = t + h*NT;            // 0..4095, 128 u32 per row
      const int row = i >> 7;
      const int c2  = i & 127;
      *(u32*)&sE1b[row*PD2 + 2*c2] = e1u[(size_t)(n0+row)*128 + c2];
    }
  }
  __syncthreads();

  const float scl = scalep[0];
  // GEMM2: t1 = silu(elec1 @ W1 + b1 + hmsg[global=out]) -> sR1
  gemm_mfma<2,1>(sE1b, sE1b, sR1, Wt + (1<<16), b1, out, nullptr, 0.f, n0, t);
  __syncthreads();
  // GEMM3: t2 = silu(t1 @ W2 + b2 + msg) -> sR1
  gemm_mfma<2,0>(sR1, sE1b, sR1, Wt + (2<<16), b2, msg, nullptr, 0.f, n0, t);
  __syncthreads();
  // GEMM4: out = (silu(t2 @ W3 + b3) + elec1) * scl
  gemm_mfma<3,0>(sR1, sE1b, sR1, Wt + (3<<16), b3, nullptr, out, scl, n0, t);
}

extern "C" void kernel_launch(void* const* d_in, const int* in_sizes, int n_in,
                              void* d_out, int out_size, void* d_ws, size_t ws_size,
                              hipStream_t stream) {
  (void)in_sizes; (void)n_in; (void)ws_size; (void)out_size;
  const float* elec  = (const float*)d_in[0];
  const float* msg   = (const float*)d_in[1];
  const float* rpos  = (const float*)d_in[2];
  const float* rnb   = (const float*)d_in[3];
  const int*   s     = (const int*)d_in[4];
  const int*   snb   = (const int*)d_in[5];
  const float* hinit = (const float*)d_in[6];
  const float* Win   = (const float*)d_in[7];
  const float* bin   = (const float*)d_in[8];
  const float* eesc  = (const float*)d_in[9];
  const float* eek   = (const float*)d_in[10];
  const float* eeb   = (const float*)d_in[11];
  const float* Wf    = (const float*)d_in[12];
  const float* bfb   = (const float*)d_in[13];
  const float* Wsame = (const float*)d_in[14];
  const float* Wdiff = (const float*)d_in[15];
  const float* W1    = (const float*)d_in[16];
  const float* b1    = (const float*)d_in[17];
  const float* W2    = (const float*)d_in[18];
  const float* b2    = (const float*)d_in[19];
  const float* W3    = (const float*)d_in[20];
  const float* b3    = (const float*)d_in[21];
  const float* scl   = (const float*)d_in[22];
  float* outp        = (float*)d_out;
  u16*   wt          = (u16*)d_ws;        // weights 0.54 MB + elec1 4 MB at E1_OFF
  u16*   elec1g      = wt + E1_OFF;

  wprep<<<dim3(1025), dim3(256), 0, stream>>>(Win, W1, W2, W3, Wsame, Wdiff, wt);
  k1_gemm1<<<dim3(NEL/ROWS), dim3(NT), 0, stream>>>(elec, bin, wt, elec1g);
  k2_msg<<<dim3(NEL), dim3(256), 0, stream>>>(
      rpos, rnb, s, snb, hinit, eesc, eek, eeb, Wf, bfb,
      wt, elec1g, outp);
  k3_gemms<<<dim3(NEL/ROWS), dim3(NT), 0, stream>>>(
      msg, elec1g, b1, b2, b3, scl, wt, outp);
}